// Round 4
// baseline (208.088 us; speedup 1.0000x reference)
//
#include <hip/hip_runtime.h>
#include <math.h>

#define BB 16
#define LL 100
#define TT 50
#define TE 100
#define HH 200
#define NTL 13               // N tiles of 16 -> 208 (pad 8)
#define NEG_INF_F (-1e30f)

typedef __bf16 bf16;
typedef bf16 bf16x8 __attribute__((ext_vector_type(8)));
typedef float f32x4 __attribute__((ext_vector_type(4)));

#define MFMA __builtin_amdgcn_mfma_f32_16x16x32_bf16

// ---------------------------------------------------------------------------
// Prep: store W^T as MFMA B-fragments, split into hi/lo bf16.
// Fragment index: (((p*NTL + nt)*4 + ks)*64 + lane)*8 + elem
//   k = ks*32 + 8*(lane>>4) + elem   (d index, zero-pad k>=100)
//   n = nt*16 + (lane&15)            (h index, zero-pad n>=200)
// ---------------------------------------------------------------------------
__global__ __launch_bounds__(256)
void wprep_kernel(const float* __restrict__ Wh, const float* __restrict__ Wr,
                  const float* __restrict__ Wt,
                  bf16* __restrict__ hi, bf16* __restrict__ lo) {
    int idx = blockIdx.x * 256 + threadIdx.x;   // grid covers exactly 3*13*2048
    int elem = idx & 7;
    int lane = (idx >> 3) & 63;
    int ks   = (idx >> 9) & 3;
    int pn   = idx >> 11;          // p*NTL + nt
    int nt   = pn % NTL;
    int p    = pn / NTL;
    int k = ks * 32 + 8 * (lane >> 4) + elem;
    int n = nt * 16 + (lane & 15);
    const float* W = (p == 0) ? Wh : (p == 1) ? Wr : Wt;
    float v = (k < TE && n < HH) ? W[n * TE + k] : 0.0f;
    bf16 h = (bf16)v;
    hi[idx] = h;
    lo[idx] = (bf16)(v - (float)h);
}

// Inline gather: fills HI[0..3], LO[0..3] (bf16x8 each) for one projection.
// All array writes at compile-time-constant indices (rule #20: SROA-friendly).
#define GATHER(SRC, HI, LO)                                                     \
    {                                                                           \
        _Pragma("unroll")                                                       \
        for (int ks_ = 0; ks_ < 4; ++ks_) {                                     \
            f32x4 v0 = {0.f, 0.f, 0.f, 0.f}, v1 = {0.f, 0.f, 0.f, 0.f};         \
            if (ks_ < 3) {                                                      \
                const int d0 = ks_ * 32 + 8 * lg;                               \
                if (rv) {                                                       \
                    v0 = *(const f32x4*)((SRC) + d0);                           \
                    v1 = *(const f32x4*)((SRC) + d0 + 4);                       \
                }                                                               \
            } else if (rv && lg == 0) {                                         \
                v0 = *(const f32x4*)((SRC) + 96);                               \
            }                                                                   \
            bf16x8 h8, l8;                                                      \
            _Pragma("unroll")                                                   \
            for (int i_ = 0; i_ < 4; ++i_) {                                    \
                bf16 a_ = (bf16)v0[i_];                                         \
                h8[i_] = a_; l8[i_] = (bf16)(v0[i_] - (float)a_);                \
                bf16 b_ = (bf16)v1[i_];                                         \
                h8[4 + i_] = b_; l8[4 + i_] = (bf16)(v1[i_] - (float)b_);        \
            }                                                                   \
            HI[ks_] = h8; LO[ks_] = l8;                                         \
        }                                                                       \
    }

__global__ __launch_bounds__(256)
void ccm_mfma_kernel(const float* __restrict__ head, const float* __restrict__ rel,
                     const float* __restrict__ tail,
                     const bf16* __restrict__ WBhi, const bf16* __restrict__ WBlo,
                     const float* __restrict__ bias_h, const float* __restrict__ bias_r,
                     const float* __restrict__ bias_t,
                     const int* __restrict__ tmask, const int* __restrict__ pmask,
                     float* __restrict__ out) {
    __shared__ float sscore[64];
    __shared__ float sattn[TT];

    const int bl  = blockIdx.x;
    const int tid = threadIdx.x;
    const int wv  = tid >> 6;       // wave = M-tile
    const int l   = tid & 63;
    const int lr  = l & 15;         // A row-in-tile / D col
    const int lg  = l >> 4;         // k-group / D row-group
    const int row = wv * 16 + lr;   // triple index
    const bool rv = row < TT;
    const size_t base0 = (size_t)bl * TT * TE;
    const size_t base  = base0 + (size_t)row * TE;

    // ---- A-fragment gather (registers only; constant indices throughout) ----
    bf16x8 HhiA[4], HloA[4], RhiA[4], RloA[4], ThiA[4], TloA[4];
    GATHER(head + base, HhiA, HloA);
    GATHER(rel  + base, RhiA, RloA);
    GATHER(tail + base, ThiA, TloA);

    // ---- MFMA loop over N tiles, fused score epilogue ----
    float sc[4] = {0.f, 0.f, 0.f, 0.f};
    const int pstride = NTL * 4 * 64 * 8;   // 26624 bf16 per projection

    #pragma unroll 1
    for (int nt = 0; nt < NTL; ++nt) {
        f32x4 aH = {0, 0, 0, 0}, aR = {0, 0, 0, 0}, aT = {0, 0, 0, 0};
        const int ob0 = nt * 2048 + l * 8;
        #pragma unroll
        for (int ks = 0; ks < 4; ++ks) {
            const int ob = ob0 + ks * 512;
            bf16x8 whH = *(const bf16x8*)(WBhi + ob);
            bf16x8 wlH = *(const bf16x8*)(WBlo + ob);
            bf16x8 whR = *(const bf16x8*)(WBhi + pstride + ob);
            bf16x8 wlR = *(const bf16x8*)(WBlo + pstride + ob);
            bf16x8 whT = *(const bf16x8*)(WBhi + 2 * pstride + ob);
            bf16x8 wlT = *(const bf16x8*)(WBlo + 2 * pstride + ob);
            aH = MFMA(HhiA[ks], whH, aH, 0, 0, 0);
            aR = MFMA(RhiA[ks], whR, aR, 0, 0, 0);
            aT = MFMA(ThiA[ks], whT, aT, 0, 0, 0);
            aH = MFMA(HloA[ks], whH, aH, 0, 0, 0);
            aR = MFMA(RloA[ks], whR, aR, 0, 0, 0);
            aT = MFMA(TloA[ks], whT, aT, 0, 0, 0);
            aH = MFMA(HhiA[ks], wlH, aH, 0, 0, 0);
            aR = MFMA(RhiA[ks], wlR, aR, 0, 0, 0);
            aT = MFMA(ThiA[ks], wlT, aT, 0, 0, 0);
        }
        // epilogue: D elem g -> (row = wv*16 + lg*4 + g, col n = nt*16 + lr)
        const int n = nt * 16 + lr;
        const bool nv = n < HH;
        const float bh = nv ? bias_h[n] : 0.f;   // n>=200: acc is 0 (zero-pad W)
        const float br = nv ? bias_r[n] : 0.f;
        const float bt = nv ? bias_t[n] : 0.f;
        #pragma unroll
        for (int g = 0; g < 4; ++g) {
            float hv  = aH[g] + bh;
            float tv  = aT[g] + bt;
            float rvv = aR[g] + br;
            float e2  = __expf(2.f * (hv + tv));
            float th  = 1.f - 2.f / (e2 + 1.f);   // tanh; saturates at +-inf
            sc[g] = fmaf(rvv, th, sc[g]);
        }
    }

    // ---- reduce score over the 16 col-lanes (masks 1,2,4,8 keep lg fixed) ----
    #pragma unroll
    for (int g = 0; g < 4; ++g) {
        float s = sc[g];
        s += __shfl_xor(s, 1);
        s += __shfl_xor(s, 2);
        s += __shfl_xor(s, 4);
        s += __shfl_xor(s, 8);
        const int trow = wv * 16 + lg * 4 + g;
        if (lr == 0 && trow < TT) sscore[trow] = s;
    }
    __syncthreads();

    // ---- softmax over T on wave 0 (mask semantics match reference order) ----
    if (tid < 64) {
        const int t = tid;
        const bool valid = t < TT;
        float lgt = valid ? sscore[t] : 0.f;
        const bool tm = valid ? (tmask[bl * TT + t] != 0) : false;
        const bool pm = pmask[bl] != 0;
        float logit = pm ? 0.f : (tm ? NEG_INF_F : lgt);
        float mx = valid ? logit : -3.0e38f;
        #pragma unroll
        for (int o = 32; o; o >>= 1) mx = fmaxf(mx, __shfl_xor(mx, o));
        float e = valid ? __expf(logit - mx) : 0.f;
        float s = e;
        #pragma unroll
        for (int o = 32; o; o >>= 1) s += __shfl_xor(s, o);
        if (valid) sattn[t] = e / s;
    }
    __syncthreads();

    // ---- aggregation: re-read head/tail from global (L1/L2-hot lines) ----
    if (tid < 2 * TE) {
        const int e = tid;
        const float* src = (e < TE ? head + base0 + e
                                   : tail + base0 + (e - TE));
        float acc = 0.f;
        #pragma unroll
        for (int t = 0; t < TT; ++t) acc = fmaf(src[t * TE], sattn[t], acc);
        out[(size_t)bl * (2 * TE) + e] = acc;
    }
}

extern "C" void kernel_launch(void* const* d_in, const int* in_sizes, int n_in,
                              void* d_out, int out_size, void* d_ws, size_t ws_size,
                              hipStream_t stream) {
    const float* head = (const float*)d_in[0];
    const float* rel  = (const float*)d_in[1];
    const float* tail = (const float*)d_in[2];
    const float* Whw  = (const float*)d_in[3];
    const float* Whb  = (const float*)d_in[4];
    const float* Wrw  = (const float*)d_in[5];
    const float* Wrb  = (const float*)d_in[6];
    const float* Wtw  = (const float*)d_in[7];
    const float* Wtb  = (const float*)d_in[8];
    const int* tmask  = (const int*)d_in[9];
    const int* pmask  = (const int*)d_in[10];
    float* out = (float*)d_out;

    bf16* WBhi = (bf16*)d_ws;                    // 79872 bf16 = 159744 B
    bf16* WBlo = WBhi + 3 * NTL * 4 * 64 * 8;

    wprep_kernel<<<(3 * NTL * 4 * 64 * 8) / 256, 256, 0, stream>>>(Whw, Wrw, Wtw, WBhi, WBlo);
    ccm_mfma_kernel<<<BB * LL, 256, 0, stream>>>(head, rel, tail, WBhi, WBlo,
                                                 Whb, Wrb, Wtb, tmask, pmask, out);
}

// Round 5
// 186.204 us; speedup vs baseline: 1.1175x; 1.1175x over previous
//
#include <hip/hip_runtime.h>
#include <math.h>

#define BB 16
#define LL 100
#define TT 50
#define TE 100
#define HH 200
#define NTL 13               // N tiles of 16 -> 208 (pad 8)
#define NEG_INF_F (-1e30f)

typedef _Float16 fp16;
typedef fp16 half8 __attribute__((ext_vector_type(8)));
typedef float f32x4 __attribute__((ext_vector_type(4)));

#define MFMA16 __builtin_amdgcn_mfma_f32_16x16x32_f16

// ---------------------------------------------------------------------------
// Prep: W^T as fp16 MFMA B-fragments, bias folded in at k==100.
// Fragment index: (((p*NTL + nt)*4 + ks)*64 + lane)*8 + elem
//   k = ks*32 + 8*(lane>>4) + elem   (d index; k==100 holds bias; pad 0)
//   n = nt*16 + (lane&15)            (h index, zero-pad n>=200)
// ---------------------------------------------------------------------------
__global__ __launch_bounds__(256)
void wprep_kernel(const float* __restrict__ Wh, const float* __restrict__ Wr,
                  const float* __restrict__ Wt,
                  const float* __restrict__ Bh, const float* __restrict__ Br,
                  const float* __restrict__ Bt,
                  fp16* __restrict__ WB) {
    int idx = blockIdx.x * 256 + threadIdx.x;   // grid covers exactly 3*NTL*2048
    int elem = idx & 7;
    int lane = (idx >> 3) & 63;
    int ks   = (idx >> 9) & 3;
    int pn   = idx >> 11;          // p*NTL + nt
    int nt   = pn % NTL;
    int p    = pn / NTL;
    int k = ks * 32 + 8 * (lane >> 4) + elem;
    int n = nt * 16 + (lane & 15);
    const float* W = (p == 0) ? Wh : (p == 1) ? Wr : Wt;
    const float* Bi = (p == 0) ? Bh : (p == 1) ? Br : Bt;
    float v = 0.0f;
    if (n < HH) {
        if (k < TE)       v = W[n * TE + k];
        else if (k == TE) v = Bi[n];           // bias row (A supplies 1.0)
    }
    WB[idx] = (fp16)v;
}

// Fill DST[0..3] (half8) with A-fragments for one 16-row tile, fp16.
// ks==3 carries k=96..99 plus the bias-activation 1.0 at k==100 (lg==0,elem4).
// All writes at compile-time indices (rule #20).
#define GATHER1(SRC, DST, RV)                                                   \
    {                                                                           \
        _Pragma("unroll")                                                       \
        for (int ks_ = 0; ks_ < 4; ++ks_) {                                     \
            f32x4 v0 = {0.f, 0.f, 0.f, 0.f}, v1 = {0.f, 0.f, 0.f, 0.f};         \
            float one_ = 0.f;                                                   \
            if (ks_ < 3) {                                                      \
                const int d0 = ks_ * 32 + 8 * lg;                               \
                if (RV) {                                                       \
                    v0 = *(const f32x4*)((SRC) + d0);                           \
                    v1 = *(const f32x4*)((SRC) + d0 + 4);                       \
                }                                                               \
            } else if ((RV) && lg == 0) {                                       \
                v0 = *(const f32x4*)((SRC) + 96);                               \
                one_ = 1.0f;                                                    \
            }                                                                   \
            half8 h8;                                                           \
            _Pragma("unroll")                                                   \
            for (int i_ = 0; i_ < 4; ++i_) {                                    \
                h8[i_]     = (fp16)v0[i_];                                      \
                h8[4 + i_] = (fp16)v1[i_];                                      \
            }                                                                   \
            if (ks_ == 3) h8[4] = (fp16)one_;   /* k==100 activation */         \
            DST[ks_] = h8;                                                      \
        }                                                                       \
    }

__global__ __launch_bounds__(128, 3)
void ccm_mfma_kernel(const float* __restrict__ head, const float* __restrict__ rel,
                     const float* __restrict__ tail,
                     const fp16* __restrict__ WB,
                     const int* __restrict__ tmask, const int* __restrict__ pmask,
                     float* __restrict__ out) {
    __shared__ float sscore[64];
    __shared__ float sattn[64];

    const int bl  = blockIdx.x;
    const int tid = threadIdx.x;
    const int wv  = tid >> 6;       // wave: 0 -> rows 0..31, 1 -> rows 32..63
    const int l   = tid & 63;
    const int lr  = l & 15;         // A row-in-tile / D col
    const int lg  = l >> 4;         // k-group / D row-group
    const int r0  = wv * 32 + lr;        // tile-0 row (triple)
    const int r1  = wv * 32 + 16 + lr;   // tile-1 row
    const bool rv0 = r0 < TT;
    const bool rv1 = r1 < TT;
    const size_t base0 = (size_t)bl * TT * TE;

    // ---- A-fragment gather: 2 M-tiles x 3 projections, fp16 (registers) ----
    half8 H0[4], R0[4], T0[4], H1[4], R1[4], T1[4];
    GATHER1(head + base0 + (size_t)r0 * TE, H0, rv0);
    GATHER1(rel  + base0 + (size_t)r0 * TE, R0, rv0);
    GATHER1(tail + base0 + (size_t)r0 * TE, T0, rv0);
    GATHER1(head + base0 + (size_t)r1 * TE, H1, rv1);
    GATHER1(rel  + base0 + (size_t)r1 * TE, R1, rv1);
    GATHER1(tail + base0 + (size_t)r1 * TE, T1, rv1);

    // ---- MFMA loop over N tiles; each weight fragment feeds 2 M-tiles ----
    float sc0[4] = {0.f, 0.f, 0.f, 0.f};
    float sc1[4] = {0.f, 0.f, 0.f, 0.f};
    const int ps = NTL * 4 * 64 * 8;   // per-projection fragment stride (26624)

    #pragma unroll 1
    for (int nt = 0; nt < NTL; ++nt) {
        f32x4 aH0 = {0,0,0,0}, aR0 = {0,0,0,0}, aT0 = {0,0,0,0};
        f32x4 aH1 = {0,0,0,0}, aR1 = {0,0,0,0}, aT1 = {0,0,0,0};
        const int ob0 = nt * 2048 + l * 8;
        #pragma unroll
        for (int ks = 0; ks < 4; ++ks) {
            const int ob = ob0 + ks * 512;
            half8 wH = *(const half8*)(WB + ob);
            half8 wR = *(const half8*)(WB + ps + ob);
            half8 wT = *(const half8*)(WB + 2 * ps + ob);
            aH0 = MFMA16(H0[ks], wH, aH0, 0, 0, 0);
            aH1 = MFMA16(H1[ks], wH, aH1, 0, 0, 0);
            aR0 = MFMA16(R0[ks], wR, aR0, 0, 0, 0);
            aR1 = MFMA16(R1[ks], wR, aR1, 0, 0, 0);
            aT0 = MFMA16(T0[ks], wT, aT0, 0, 0, 0);
            aT1 = MFMA16(T1[ks], wT, aT1, 0, 0, 0);
        }
        // epilogue (bias already folded): tanh + r*th, both tiles
        #pragma unroll
        for (int g = 0; g < 4; ++g) {
            float s0 = aH0[g] + aT0[g];
            float e0 = __expf(2.f * s0);
            float t0 = 1.f - 2.f / (e0 + 1.f);
            sc0[g] = fmaf(aR0[g], t0, sc0[g]);
            float s1 = aH1[g] + aT1[g];
            float e1 = __expf(2.f * s1);
            float t1 = 1.f - 2.f / (e1 + 1.f);
            sc1[g] = fmaf(aR1[g], t1, sc1[g]);
        }
    }

    // ---- reduce scores over the 16 col-lanes (masks 1,2,4,8 keep lg) ----
    #pragma unroll
    for (int g = 0; g < 4; ++g) {
        float s = sc0[g];
        s += __shfl_xor(s, 1); s += __shfl_xor(s, 2);
        s += __shfl_xor(s, 4); s += __shfl_xor(s, 8);
        const int tr = wv * 32 + lg * 4 + g;
        if (lr == 0 && tr < TT) sscore[tr] = s;
        float s1 = sc1[g];
        s1 += __shfl_xor(s1, 1); s1 += __shfl_xor(s1, 2);
        s1 += __shfl_xor(s1, 4); s1 += __shfl_xor(s1, 8);
        const int tr1 = wv * 32 + 16 + lg * 4 + g;
        if (lr == 0 && tr1 < TT) sscore[tr1] = s1;
    }
    __syncthreads();

    // ---- softmax over T on wave 0 (mask semantics match reference) ----
    if (tid < 64) {
        const int t = tid;
        const bool valid = t < TT;
        float lgt = valid ? sscore[t] : 0.f;
        const bool tm = valid ? (tmask[bl * TT + t] != 0) : false;
        const bool pm = pmask[bl] != 0;
        float logit = pm ? 0.f : (tm ? NEG_INF_F : lgt);
        float mx = valid ? logit : -3.0e38f;
        #pragma unroll
        for (int o = 32; o; o >>= 1) mx = fmaxf(mx, __shfl_xor(mx, o));
        float e = valid ? __expf(logit - mx) : 0.f;
        float s = e;
        #pragma unroll
        for (int o = 32; o; o >>= 1) s += __shfl_xor(s, o);
        if (valid) sattn[t] = e / s;
    }
    __syncthreads();

    // ---- aggregation: re-read head/tail from global (L2-hot lines) ----
    for (int e = tid; e < 2 * TE; e += 128) {
        const float* src = (e < TE ? head + base0 + e
                                   : tail + base0 + (e - TE));
        float acc = 0.f;
        #pragma unroll
        for (int t = 0; t < TT; ++t) acc = fmaf(src[t * TE], sattn[t], acc);
        out[(size_t)bl * (2 * TE) + e] = acc;
    }
}

extern "C" void kernel_launch(void* const* d_in, const int* in_sizes, int n_in,
                              void* d_out, int out_size, void* d_ws, size_t ws_size,
                              hipStream_t stream) {
    const float* head = (const float*)d_in[0];
    const float* rel  = (const float*)d_in[1];
    const float* tail = (const float*)d_in[2];
    const float* Whw  = (const float*)d_in[3];
    const float* Whb  = (const float*)d_in[4];
    const float* Wrw  = (const float*)d_in[5];
    const float* Wrb  = (const float*)d_in[6];
    const float* Wtw  = (const float*)d_in[7];
    const float* Wtb  = (const float*)d_in[8];
    const int* tmask  = (const int*)d_in[9];
    const int* pmask  = (const int*)d_in[10];
    float* out = (float*)d_out;

    fp16* WB = (fp16*)d_ws;   // 3*NTL*2048 fp16 = 159744 B

    wprep_kernel<<<(3 * NTL * 2048) / 256, 256, 0, stream>>>(Whw, Wrw, Wtw,
                                                             Whb, Wrb, Wtb, WB);
    ccm_mfma_kernel<<<BB * LL, 128, 0, stream>>>(head, rel, tail, WB,
                                                 tmask, pmask, out);
}

// Round 6
// 178.968 us; speedup vs baseline: 1.1627x; 1.0404x over previous
//
#include <hip/hip_runtime.h>
#include <math.h>

#define BB 16
#define LL 100
#define TT 50
#define TE 100
#define HH 200
#define NTL 13               // N tiles of 16 -> 208 (pad 8)
#define NEG_INF_F (-1e30f)

typedef _Float16 fp16;
typedef fp16 half8 __attribute__((ext_vector_type(8)));
typedef float f32x4 __attribute__((ext_vector_type(4)));

#define MFMA16 __builtin_amdgcn_mfma_f32_16x16x32_f16

// ---------------------------------------------------------------------------
// Prep: W^T as fp16 MFMA B-fragments, bias folded in at k==100.
// NEW layout (stage-friendly): idx = (((nt*3 + p)*4 + ks)*64 + lane)*8 + elem
// so each nt-chunk is 6144 fp16 = 12 KB contiguous.
//   k = ks*32 + 8*(lane>>4) + elem   (d index; k==100 holds bias; pad 0)
//   n = nt*16 + (lane&15)            (h index, zero-pad n>=200)
// ---------------------------------------------------------------------------
__global__ __launch_bounds__(256)
void wprep_kernel(const float* __restrict__ Wh, const float* __restrict__ Wr,
                  const float* __restrict__ Wt,
                  const float* __restrict__ Bh, const float* __restrict__ Br,
                  const float* __restrict__ Bt,
                  fp16* __restrict__ WB) {
    int idx = blockIdx.x * 256 + threadIdx.x;   // grid covers exactly NTL*3*2048
    int elem = idx & 7;
    int lane = (idx >> 3) & 63;
    int ks   = (idx >> 9) & 3;
    int np   = idx >> 11;          // nt*3 + p
    int p    = np % 3;
    int nt   = np / 3;
    int k = ks * 32 + 8 * (lane >> 4) + elem;
    int n = nt * 16 + (lane & 15);
    const float* W  = (p == 0) ? Wh : (p == 1) ? Wr : Wt;
    const float* Bi = (p == 0) ? Bh : (p == 1) ? Br : Bt;
    float v = 0.0f;
    if (n < HH) {
        if (k < TE)       v = W[n * TE + k];
        else if (k == TE) v = Bi[n];           // bias row (A supplies 1.0)
    }
    WB[idx] = (fp16)v;
}

// Fill DST[0..3] (half8) with A-fragments for one 16-row tile, fp16.
// ks==3 carries k=96..99 plus the bias-activation 1.0 at k==100 (lg==0,elem4).
// All writes at compile-time indices (rule #20).
#define GATHER1(SRC, DST, RV)                                                   \
    {                                                                           \
        _Pragma("unroll")                                                       \
        for (int ks_ = 0; ks_ < 4; ++ks_) {                                     \
            f32x4 v0 = {0.f, 0.f, 0.f, 0.f}, v1 = {0.f, 0.f, 0.f, 0.f};         \
            float one_ = 0.f;                                                   \
            if (ks_ < 3) {                                                      \
                const int d0 = ks_ * 32 + 8 * lg;                               \
                if (RV) {                                                       \
                    v0 = *(const f32x4*)((SRC) + d0);                           \
                    v1 = *(const f32x4*)((SRC) + d0 + 4);                       \
                }                                                               \
            } else if ((RV) && lg == 0) {                                       \
                v0 = *(const f32x4*)((SRC) + 96);                               \
                one_ = 1.0f;                                                    \
            }                                                                   \
            half8 h8;                                                           \
            _Pragma("unroll")                                                   \
            for (int i_ = 0; i_ < 4; ++i_) {                                    \
                h8[i_]     = (fp16)v0[i_];                                      \
                h8[4 + i_] = (fp16)v1[i_];                                      \
            }                                                                   \
            if (ks_ == 3) h8[4] = (fp16)one_;   /* k==100 activation */         \
            DST[ks_] = h8;                                                      \
        }                                                                       \
    }

// Stage 3 of the 12 1-KB units of one nt-chunk (this wave's share).
// LDS dest is wave-uniform base; HW adds lane*16. Global src is per-lane.
#define STAGE3(GBASE, LBASE)                                                    \
    {                                                                           \
        _Pragma("unroll")                                                       \
        for (int u_ = 0; u_ < 3; ++u_) {                                        \
            const int unit_ = wv * 3 + u_;                                      \
            __builtin_amdgcn_global_load_lds(                                   \
                (const __attribute__((address_space(1))) unsigned int*)         \
                    ((GBASE) + unit_ * 512 + l * 8),                            \
                (__attribute__((address_space(3))) unsigned int*)               \
                    ((LBASE) + unit_ * 512),                                    \
                16, 0, 0);                                                      \
        }                                                                       \
    }

__global__ __launch_bounds__(256, 3)
void ccm_mfma_kernel(const float* __restrict__ head, const float* __restrict__ rel,
                     const float* __restrict__ tail,
                     const fp16* __restrict__ WB,
                     const int* __restrict__ tmask, const int* __restrict__ pmask,
                     float* __restrict__ out) {
    __shared__ fp16 sw[2][6144];      // double-buffered nt-chunk: [p*4+ks][lane][8]
    __shared__ float sscore[2][64];
    __shared__ float sattn[2][64];

    const int tid = threadIdx.x;
    const int wv  = tid >> 6;         // wave 0..3
    const int l   = tid & 63;
    const int lr  = l & 15;           // A row-in-tile / D col
    const int lg  = l >> 4;           // k-group / D row-group
    const int blx = wv >> 1;          // which (b,l) this wave serves (0/1)
    const int wp  = wv & 1;           // row-half: 0 -> rows 0..31, 1 -> 32..63
    const int bl  = 2 * blockIdx.x + blx;
    const int r0  = wp * 32 + lr;         // tile-a row (triple)
    const int r1  = wp * 32 + 16 + lr;    // tile-b row
    const bool rv0 = r0 < TT;
    const bool rv1 = r1 < TT;
    const size_t base0 = (size_t)bl * TT * TE;

    // ---- A-fragment gather: 2 M-tiles x 3 projections, fp16 (registers) ----
    half8 H0[4], R0[4], T0[4], H1[4], R1[4], T1[4];
    GATHER1(head + base0 + (size_t)r0 * TE, H0, rv0);
    GATHER1(rel  + base0 + (size_t)r0 * TE, R0, rv0);
    GATHER1(tail + base0 + (size_t)r0 * TE, T0, rv0);
    GATHER1(head + base0 + (size_t)r1 * TE, H1, rv1);
    GATHER1(rel  + base0 + (size_t)r1 * TE, R1, rv1);
    GATHER1(tail + base0 + (size_t)r1 * TE, T1, rv1);

    // ---- prologue: stage nt=0 into buffer 0 ----
    STAGE3(WB, &sw[0][0]);

    float sc0[4] = {0.f, 0.f, 0.f, 0.f};
    float sc1[4] = {0.f, 0.f, 0.f, 0.f};

    #pragma unroll 1
    for (int nt = 0; nt < NTL; ++nt) {
        const int cur = nt & 1;
        if (nt + 1 < NTL) {
            STAGE3(WB + (size_t)(nt + 1) * 6144, &sw[cur ^ 1][0]);
            __builtin_amdgcn_sched_barrier(0);
            asm volatile("s_waitcnt vmcnt(3)" ::: "memory");  // my 3 units for buf[cur] done
        } else {
            __builtin_amdgcn_sched_barrier(0);
            asm volatile("s_waitcnt vmcnt(0)" ::: "memory");
        }
        __syncthreads();                                      // everyone's units visible

        const fp16* wbuf = (const fp16*)&sw[cur][0];
        f32x4 aH0 = {0,0,0,0}, aR0 = {0,0,0,0}, aT0 = {0,0,0,0};
        f32x4 aH1 = {0,0,0,0}, aR1 = {0,0,0,0}, aT1 = {0,0,0,0};
        #pragma unroll
        for (int ks = 0; ks < 4; ++ks) {
            half8 wH = *(const half8*)(wbuf + (0 * 4 + ks) * 512 + l * 8);
            half8 wR = *(const half8*)(wbuf + (1 * 4 + ks) * 512 + l * 8);
            half8 wT = *(const half8*)(wbuf + (2 * 4 + ks) * 512 + l * 8);
            aH0 = MFMA16(H0[ks], wH, aH0, 0, 0, 0);
            aH1 = MFMA16(H1[ks], wH, aH1, 0, 0, 0);
            aR0 = MFMA16(R0[ks], wR, aR0, 0, 0, 0);
            aR1 = MFMA16(R1[ks], wR, aR1, 0, 0, 0);
            aT0 = MFMA16(T0[ks], wT, aT0, 0, 0, 0);
            aT1 = MFMA16(T1[ks], wT, aT1, 0, 0, 0);
        }
        // epilogue (bias folded in K): tanh + r*th, both tiles
        #pragma unroll
        for (int g = 0; g < 4; ++g) {
            float s0 = aH0[g] + aT0[g];
            float e0 = __expf(2.f * s0);
            float t0 = 1.f - 2.f / (e0 + 1.f);
            sc0[g] = fmaf(aR0[g], t0, sc0[g]);
            float s1 = aH1[g] + aT1[g];
            float e1 = __expf(2.f * s1);
            float t1 = 1.f - 2.f / (e1 + 1.f);
            sc1[g] = fmaf(aR1[g], t1, sc1[g]);
        }
        __syncthreads();                                      // reads done before overwrite
    }

    // ---- reduce scores over the 16 col-lanes (masks 1,2,4,8 keep lg) ----
    #pragma unroll
    for (int g = 0; g < 4; ++g) {
        float s = sc0[g];
        s += __shfl_xor(s, 1); s += __shfl_xor(s, 2);
        s += __shfl_xor(s, 4); s += __shfl_xor(s, 8);
        const int tr = wp * 32 + lg * 4 + g;
        if (lr == 0 && tr < TT) sscore[blx][tr] = s;
        float s1 = sc1[g];
        s1 += __shfl_xor(s1, 1); s1 += __shfl_xor(s1, 2);
        s1 += __shfl_xor(s1, 4); s1 += __shfl_xor(s1, 8);
        const int tr1 = wp * 32 + 16 + lg * 4 + g;
        if (lr == 0 && tr1 < TT) sscore[blx][tr1] = s1;
    }
    __syncthreads();

    // ---- softmax: wave 0 -> bl0, wave 1 -> bl1 ----
    if (tid < 128) {
        const int bx = tid >> 6;
        const int t  = tid & 63;
        const int mybl = 2 * blockIdx.x + bx;
        const bool valid = t < TT;
        float lgt = valid ? sscore[bx][t] : 0.f;
        const bool tm = valid ? (tmask[mybl * TT + t] != 0) : false;
        const bool pm = pmask[mybl] != 0;
        float logit = pm ? 0.f : (tm ? NEG_INF_F : lgt);
        float mx = valid ? logit : -3.0e38f;
        #pragma unroll
        for (int o = 32; o; o >>= 1) mx = fmaxf(mx, __shfl_xor(mx, o));
        float e = valid ? __expf(logit - mx) : 0.f;
        float s = e;
        #pragma unroll
        for (int o = 32; o; o >>= 1) s += __shfl_xor(s, o);
        if (valid) sattn[bx][t] = e / s;
    }
    __syncthreads();

    // ---- aggregation: re-read head/tail from global (cache-hot lines) ----
    #pragma unroll
    for (int it = 0; it < 2; ++it) {
        const int i = tid + it * 256;
        if (i < 2 * (2 * TE)) {
            const int bx = (i >= 2 * TE) ? 1 : 0;
            const int e  = i - bx * (2 * TE);
            const size_t b2 = (size_t)(2 * blockIdx.x + bx) * TT * TE;
            const float* src = (e < TE) ? head + b2 + e : tail + b2 + (e - TE);
            float acc = 0.f;
            #pragma unroll
            for (int t = 0; t < TT; ++t) acc = fmaf(src[t * TE], sattn[bx][t], acc);
            out[(size_t)(2 * blockIdx.x + bx) * (2 * TE) + e] = acc;
        }
    }
}

extern "C" void kernel_launch(void* const* d_in, const int* in_sizes, int n_in,
                              void* d_out, int out_size, void* d_ws, size_t ws_size,
                              hipStream_t stream) {
    const float* head = (const float*)d_in[0];
    const float* rel  = (const float*)d_in[1];
    const float* tail = (const float*)d_in[2];
    const float* Whw  = (const float*)d_in[3];
    const float* Whb  = (const float*)d_in[4];
    const float* Wrw  = (const float*)d_in[5];
    const float* Wrb  = (const float*)d_in[6];
    const float* Wtw  = (const float*)d_in[7];
    const float* Wtb  = (const float*)d_in[8];
    const int* tmask  = (const int*)d_in[9];
    const int* pmask  = (const int*)d_in[10];
    float* out = (float*)d_out;

    fp16* WB = (fp16*)d_ws;   // NTL*3*2048 fp16 = 159744 B

    wprep_kernel<<<(NTL * 3 * 2048) / 256, 256, 0, stream>>>(Whw, Wrw, Wtw,
                                                             Whb, Wrb, Wtb, WB);
    ccm_mfma_kernel<<<(BB * LL) / 2, 256, 0, stream>>>(head, rel, tail, WB,
                                                       tmask, pmask, out);
}